// Round 8
// baseline (55.217 us; speedup 1.0000x reference)
//
#include <hip/hip_runtime.h>

#define BITS 108
#define F4PR 27                 // float4s (nibbles) per row
#define ACT  54                 // active lanes per wave = 2 rows
#define NPAIRS 131072           // row-pairs total (262144 rows / 2)
#define NBLK 2048               // persistent blocks
#define TPB  256                // 8192 waves, 16 row-pairs each

typedef float f32x4 __attribute__((ext_vector_type(4)));

// One wave = 2 rows per iteration. Lane l<27: row pos l of first row;
// 27<=l<54: pos l-27 of second row; lanes 54..63 duplicate lane 53's load.
// Carry prefix via ballot masks + the hardware adder:
//   g,p mutually exclusive => carries of (g|p)+g follow c_{i+1}=g_i|(p_i&c_i).
__global__ __launch_bounds__(TPB) void rca108_kernel(
    const f32x4* __restrict__ A4, const f32x4* __restrict__ B4,
    f32x4* __restrict__ S4, float* __restrict__ C)
{
    const int l     = threadIdx.x & 63;
    const int half  = (l >= F4PR) ? 1 : 0;        // which row of the pair
    const int pos   = l - half * F4PR;            // nibble index (junk >=27 for idle)
    const int lidx  = (l < ACT) ? l : (ACT - 1);  // idle lanes duplicate lane 53
    const int wid0  = (blockIdx.x * TPB + threadIdx.x) >> 6;
    const int nwav  = (NBLK * TPB) >> 6;          // 8192

    #pragma unroll 2
    for (int w = wid0; w < NPAIRS; w += nwav) {
        const size_t g = (size_t)w * ACT + lidx;  // float4 index
        const f32x4 av = A4[g];
        const f32x4 bv = B4[g];
        const unsigned an = (unsigned)(av.x > 0.5f)
                          | ((unsigned)(av.y > 0.5f) << 1)
                          | ((unsigned)(av.z > 0.5f) << 2)
                          | ((unsigned)(av.w > 0.5f) << 3);
        const unsigned bn = (unsigned)(bv.x > 0.5f)
                          | ((unsigned)(bv.y > 0.5f) << 1)
                          | ((unsigned)(bv.z > 0.5f) << 2)
                          | ((unsigned)(bv.w > 0.5f) << 3);
        const unsigned sum = an + bn;                      // 0..30

        const unsigned long long gm = __ballot(sum >= 16u);  // generate
        const unsigned long long pm = __ballot(sum == 15u);  // propagate

        // this lane's row masks (27 bits)
        const unsigned rg = (unsigned)(gm >> (half * F4PR)) & 0x7FFFFFFu;
        const unsigned rp = (unsigned)(pm >> (half * F4PR)) & 0x7FFFFFFu;
        const unsigned q  = rg | rp;
        const unsigned k  = (q + rg) ^ q ^ rg;   // bit i = carry INTO nibble i
        const unsigned cin = (k >> pos) & 1u;
        const unsigned s   = sum + cin;          // 5 bits

        f32x4 out;
        out.x = (float)( s       & 1u);
        out.y = (float)((s >> 1) & 1u);
        out.z = (float)((s >> 2) & 1u);
        out.w = (float)((s >> 3) & 1u);
        if (l < ACT) {
            __builtin_nontemporal_store(out, &S4[g]);
            if (pos == F4PR - 1)                  // top nibble: row carry-out
                __builtin_nontemporal_store((float)(s >> 4), &C[2 * w + half]);
        }
    }
}

extern "C" void kernel_launch(void* const* d_in, const int* in_sizes, int n_in,
                              void* d_out, int out_size, void* d_ws, size_t ws_size,
                              hipStream_t stream) {
    const f32x4* A4 = (const f32x4*)d_in[0];
    const f32x4* B4 = (const f32x4*)d_in[1];
    float* S = (float*)d_out;                     // [nrows, 108] flat
    const int nrows = in_sizes[0] / BITS;         // 262144
    float* C = S + (size_t)nrows * BITS;          // [nrows, 1] after S
    (void)nrows;

    rca108_kernel<<<NBLK, TPB, 0, stream>>>(A4, B4, (f32x4*)S, C);
}

// Round 9
// 52.760 us; speedup vs baseline: 1.0466x; 1.0466x over previous
//
#include <hip/hip_runtime.h>

#define BITS 108
#define F4PR 27                 // float4s (nibbles) per row
#define ACT  54                 // active lanes per wave = 2 rows

typedef float f32x4 __attribute__((ext_vector_type(4)));
typedef unsigned int u32x4 __attribute__((ext_vector_type(4)));

// One wave = 2 rows, one-shot (R7 grid). Lane l<27: nibble l of row 2w;
// 27<=l<54: nibble l-27 of row 2w+1; lanes 54..63 duplicate lane 53's load.
// Inputs are exactly 0.0f/1.0f -> bit 29 of the IEEE pattern is the value.
// Carry prefix via ballot masks + hardware adder: g,p mutually exclusive =>
// carries of (g|p)+g obey c_{i+1} = g_i | (p_i & c_i)  (k = (q+g)^q^g).
__global__ __launch_bounds__(256) void rca108_kernel(
    const u32x4* __restrict__ A4, const u32x4* __restrict__ B4,
    f32x4* __restrict__ S4, float* __restrict__ C)
{
    const int gtid = blockIdx.x * blockDim.x + threadIdx.x;
    const int wid  = gtid >> 6;                  // global wave id = row pair
    const int l    = threadIdx.x & 63;
    const int half = (l >= F4PR) ? 1 : 0;        // which row of the pair
    const int pos  = l - half * F4PR;            // nibble index within row
    const int lidx = (l < ACT) ? l : (ACT - 1);  // idle lanes duplicate lane 53
    const size_t g = (size_t)wid * ACT + lidx;   // float4 index

    const u32x4 av = A4[g];
    const u32x4 bv = B4[g];
    const unsigned an = ((av.x >> 29) & 1u) | ((av.y >> 28) & 2u)
                      | ((av.z >> 27) & 4u) | ((av.w >> 26) & 8u);
    const unsigned bn = ((bv.x >> 29) & 1u) | ((bv.y >> 28) & 2u)
                      | ((bv.z >> 27) & 4u) | ((bv.w >> 26) & 8u);
    const unsigned sum = an + bn;                        // 0..30

    const unsigned long long gm = __ballot(sum >= 16u);  // nibble generate
    const unsigned long long pm = __ballot(sum == 15u);  // nibble propagate

    // this lane's row masks (27 bits); junk bits 54..63 masked off
    const unsigned rg = (unsigned)(gm >> (half * F4PR)) & 0x7FFFFFFu;
    const unsigned rp = (unsigned)(pm >> (half * F4PR)) & 0x7FFFFFFu;
    const unsigned q  = rg | rp;
    const unsigned k  = (q + rg) ^ q ^ rg;   // bit i = carry INTO nibble i
    const unsigned cin = (k >> pos) & 1u;
    const unsigned s   = sum + cin;          // 5 bits

    f32x4 out;
    out.x = (float)( s       & 1u);
    out.y = (float)((s >> 1) & 1u);
    out.z = (float)((s >> 2) & 1u);
    out.w = (float)((s >> 3) & 1u);
    if (l < ACT) {
        __builtin_nontemporal_store(out, &S4[g]);
        if (pos == F4PR - 1)                  // top nibble: row carry-out
            __builtin_nontemporal_store((float)(s >> 4), &C[2 * wid + half]);
    }
}

extern "C" void kernel_launch(void* const* d_in, const int* in_sizes, int n_in,
                              void* d_out, int out_size, void* d_ws, size_t ws_size,
                              hipStream_t stream) {
    const u32x4* A4 = (const u32x4*)d_in[0];
    const u32x4* B4 = (const u32x4*)d_in[1];
    float* S = (float*)d_out;                     // [nrows, 108] flat
    const int nrows = in_sizes[0] / BITS;         // 262144
    float* C = S + (size_t)nrows * BITS;          // [nrows, 1] after S

    const int nwaves = nrows / 2;                 // 131072
    const int block = 256;
    const int grid = (nwaves * 64) / block;       // 32768 (exact)
    rca108_kernel<<<grid, block, 0, stream>>>(A4, B4, (f32x4*)S, C);
}